// Round 17
// baseline (143.704 us; speedup 1.0000x reference)
//
#include <hip/hip_runtime.h>
#include <cstddef>

#define P_ 4096
#define PW_ 66   // padded width/height

using u16 = unsigned short;
typedef float  f32x4  __attribute__((ext_vector_type(4)));
typedef u16    u16x8  __attribute__((ext_vector_type(8)));
typedef u16    u16x4  __attribute__((ext_vector_type(4)));
typedef __bf16 bf16x8 __attribute__((ext_vector_type(8)));

#define DEVINL __device__ __forceinline__

DEVINL u16 f2bf(float f) {
    union { float f; unsigned u; } v; v.f = f;
    unsigned r = v.u + 0x7fffu + ((v.u >> 16) & 1u);
    return (u16)(r >> 16);
}
DEVINL float bf2f(u16 h) {
    union { unsigned u; float f; } v; v.u = ((unsigned)h) << 16;
    return v.f;
}

DEVINL f32x4 mfma16(u16x8 a, u16x8 b, f32x4 c) {
    return __builtin_amdgcn_mfma_f32_16x16x32_bf16(
        __builtin_bit_cast(bf16x8, a), __builtin_bit_cast(bf16x8, b), c, 0, 0, 0);
}

DEVINL void gload16(const u16* src, const u16* lds_dst) {
    __builtin_amdgcn_global_load_lds(
        (const __attribute__((address_space(1))) void*)src,
        (__attribute__((address_space(3))) void*)lds_dst, 16, 0, 0);
}

// ---------------------------------------------------------------------------
// NCHW fp32 -> padded NHWC bf16 (+ pad-ring zeroing by y==0 blocks).
// blockIdx.x >= 64: weight-prep blocks. grid (64+75, 4, 8), 256 thr.
// ---------------------------------------------------------------------------
__global__ __launch_bounds__(256) void to_nhwc_pad(
    const float* __restrict__ in, u16* __restrict__ xp,
    const float* __restrict__ off_w, const float* __restrict__ attn_w,
    const float* __restrict__ val_w, const float* __restrict__ proj_w,
    const float* __restrict__ w1, const float* __restrict__ w2,
    u16* __restrict__ wbf) {
    const int bx = blockIdx.x, c0 = blockIdx.y * 64, b = blockIdx.z;
    const int t = threadIdx.x;

    if (bx >= 64) {   // weight prep: 2400 virtual blocks x 256 elems
        const int idx = ((bx - 64) * 32 + blockIdx.y * 8 + b) * 256 + t;
        if (idx >= 614400) return;
        float v;
        if (idx < 221184) {
            int tap = idx / 24576, rem = idx - tap * 24576, oc = rem >> 8, ic = rem & 255;
            v = (oc < 64) ? off_w[(size_t)(oc * 256 + ic) * 9 + tap]
                          : attn_w[(size_t)((oc - 64) * 256 + ic) * 9 + tap];
        } else if (idx < 286720) v = val_w[idx - 221184];
        else if (idx < 352256)   v = proj_w[idx - 286720];
        else if (idx < 483328)   v = w1[idx - 352256];
        else                     v = w2[idx - 483328];
        wbf[idx] = f2bf(v);
        return;
    }

    const int y = bx;
    __shared__ u16 ts[64 * 72];
    const int cl = t >> 4, xq = t & 15;

    if (y == 0) {   // zero pad ring for this channel range
        const u16x8 z = (u16x8){0, 0, 0, 0, 0, 0, 0, 0};
        for (int q = t; q < 2080; q += 256) {
            const int p = q >> 3, c8 = q & 7;
            int row, col;
            if (p < 66)       { row = 0;  col = p; }
            else if (p < 132) { row = 65; col = p - 66; }
            else { const int q2 = p - 132; row = 1 + (q2 >> 1); col = (q2 & 1) * 65; }
            *(u16x8*)&xp[((size_t)(b * PW_ + row) * PW_ + col) * 256 + c0 + c8 * 8] = z;
        }
    }

    #pragma unroll
    for (int r = 0; r < 4; ++r) {
        const int c = r * 16 + cl;
        const float4 v = *(const float4*)&in[((size_t)(b * 256 + c0 + c)) * P_ + y * 64 + xq * 4];
        ts[(xq * 4 + 0) * 72 + c] = f2bf(v.x);
        ts[(xq * 4 + 1) * 72 + c] = f2bf(v.y);
        ts[(xq * 4 + 2) * 72 + c] = f2bf(v.z);
        ts[(xq * 4 + 3) * 72 + c] = f2bf(v.w);
    }
    __syncthreads();
    const int px = t >> 2, seg = t & 3;
    u16x8 o0, o1;
    #pragma unroll
    for (int j = 0; j < 8; ++j) {
        o0[j] = ts[px * 72 + seg * 16 + j];
        o1[j] = ts[px * 72 + seg * 16 + 8 + j];
    }
    const size_t base = ((size_t)(b * PW_ + y + 1) * PW_ + 1 + px) * 256 + c0 + seg * 16;
    *(u16x8*)&xp[base]     = o0;
    *(u16x8*)&xp[base + 8] = o1;
}

// ---------------------------------------------------------------------------
// Fused dispatch: even blocks = conv3x3 (R15 body, 18-chunk dbuf pipeline),
// odd blocks = value 1x1 GEMM (R15 gemm_dbuf mode-0 body, padded input).
// Both paths 2 blocks/CU; co-residency lets value's MFMA work fill conv's
// latency bubbles. grid (1024), 256 thr, LDS 80KB shared by both paths.
// ---------------------------------------------------------------------------
__global__ __launch_bounds__(256, 2) void conv_value(
    const u16* __restrict__ xp, const u16* __restrict__ wconv,
    const u16* __restrict__ wval,
    const float* __restrict__ off_b, const float* __restrict__ attn_b,
    const float* __restrict__ val_b,
    u16* __restrict__ convout, u16* __restrict__ value_bf) {
    const int bid = blockIdx.x;
    const int id = bid >> 1;
    const int tid = threadIdx.x, w = tid >> 6, lane = tid & 63, g = lane >> 4, i = lane & 15;
    const int wm = w & 1, wn = w >> 1;
    __shared__ u16 lds[40960];           // 80 KB

    if ((bid & 1) == 0) {
        // ---------------- conv path: y = id&63, b = id>>6 ----------------
        const int y = id & 63, b = id >> 6;
        const int srow = lane >> 4, sc = lane & 15;

        f32x4 acc[2][3];
        #pragma unroll
        for (int mi = 0; mi < 2; ++mi)
            #pragma unroll
            for (int nj = 0; nj < 3; ++nj) acc[mi][nj] = (f32x4){0.f, 0.f, 0.f, 0.f};

        auto stage = [&](int buf, int c) {
            const int tap = c >> 1, kc = (c & 1) * 128;
            const int dy = tap / 3, dx = tap % 3;
            const u16* xrow = xp + ((size_t)(b * PW_ + y + dy) * PW_ + dx) * 256;
            const u16* wt = wconv + (size_t)(tap * 96) * 256;
            u16* bufA = &lds[buf * 8192];
            u16* bufW = &lds[16384 + buf * 12288];
            #pragma unroll
            for (int t = 0; t < 4; ++t) {
                const int j = w * 4 + t;
                const int row = j * 4 + srow;              // x 0..63
                const int cs = sc ^ (row & 7);
                gload16(xrow + (size_t)row * 256 + kc + (cs << 3), &bufA[j * 512]);
            }
            #pragma unroll
            for (int t = 0; t < 6; ++t) {
                const int j = w * 6 + t;
                const int row = j * 4 + srow;              // oc 0..95
                const int cs = sc ^ (row & 7);
                gload16(wt + (size_t)row * 256 + kc + (cs << 3), &bufW[j * 512]);
            }
        };

        stage(0, 0);
        stage(1, 1);
        asm volatile("s_waitcnt vmcnt(10)" ::: "memory");
        __builtin_amdgcn_s_barrier();

        for (int c = 0; c < 18; ++c) {
            const u16* bufA = &lds[(c & 1) * 8192];
            const u16* bufW = &lds[16384 + (c & 1) * 12288];
            #pragma unroll
            for (int ks = 0; ks < 4; ++ks) {
                u16x8 a[2], bb[3];
                #pragma unroll
                for (int mi = 0; mi < 2; ++mi) {
                    const int pr = wm * 32 + mi * 16 + i;
                    a[mi] = *(const u16x8*)&bufA[pr * 128 + (((ks * 4 + g) ^ (pr & 7)) << 3)];
                }
                #pragma unroll
                for (int nj = 0; nj < 3; ++nj) {
                    const int ocr = wn * 48 + nj * 16 + i;
                    bb[nj] = *(const u16x8*)&bufW[ocr * 128 + (((ks * 4 + g) ^ (ocr & 7)) << 3)];
                }
                #pragma unroll
                for (int mi = 0; mi < 2; ++mi)
                    #pragma unroll
                    for (int nj = 0; nj < 3; ++nj)
                        acc[mi][nj] = mfma16(a[mi], bb[nj], acc[mi][nj]);
            }
            __builtin_amdgcn_sched_barrier(0);
            __builtin_amdgcn_s_barrier();
            if (c + 2 < 18) {
                stage(c & 1, c + 2);
                asm volatile("s_waitcnt vmcnt(10)" ::: "memory");
            } else {
                asm volatile("s_waitcnt vmcnt(0)" ::: "memory");
            }
            __builtin_amdgcn_s_barrier();
        }

        #pragma unroll
        for (int mi = 0; mi < 2; ++mi) {
            const int x0 = wm * 32 + mi * 16 + g * 4;
            #pragma unroll
            for (int nj = 0; nj < 3; ++nj) {
                const int oc = wn * 48 + nj * 16 + i;
                const float bv = (oc < 64) ? off_b[oc] : attn_b[oc - 64];
                #pragma unroll
                for (int r = 0; r < 4; ++r)
                    convout[((size_t)(b * P_ + y * 64 + x0 + r)) * 96 + oc] =
                        f2bf(acc[mi][nj][r] + bv);
            }
        }
    } else {
        // ------------- value path: px0=(id&31)*128, oc0, b ---------------
        const int px0 = (id & 31) * 128, oc0 = ((id >> 5) & 1) * 128, b = id >> 6;
        u16* xs = lds;
        u16* wsL = lds + 16384;
        const int srcC = (lane & 7) ^ ((lane >> 3) & 7);

        f32x4 acc[4][4];
        #pragma unroll
        for (int mi = 0; mi < 4; ++mi)
            #pragma unroll
            for (int nj = 0; nj < 4; ++nj) acc[mi][nj] = (f32x4){0.f, 0.f, 0.f, 0.f};

        auto stage = [&](int buf, int kc) {
            #pragma unroll
            for (int t = 0; t < 4; ++t) {
                const int j = w * 4 + t;
                const int row = j * 8 + (lane >> 3);
                const int pxg = px0 + row;
                gload16(xp + ((size_t)(b * PW_ + (pxg >> 6) + 1) * PW_ + (pxg & 63) + 1) * 256
                           + kc + (srcC << 3),
                        &xs[buf * 8192 + j * 512]);
            }
            #pragma unroll
            for (int t = 0; t < 4; ++t) {
                const int j = w * 4 + t;
                const int row = j * 8 + (lane >> 3);
                gload16(wval + (size_t)(oc0 + row) * 256 + kc + (srcC << 3),
                        &wsL[buf * 8192 + j * 512]);
            }
        };

        stage(0, 0);
        stage(1, 64);
        asm volatile("s_waitcnt vmcnt(8)" ::: "memory");
        __builtin_amdgcn_s_barrier();

        for (int c = 0; c < 4; ++c) {
            const u16* xb = &xs[(c & 1) * 8192];
            const u16* wb = &wsL[(c & 1) * 8192];
            #pragma unroll
            for (int ks = 0; ks < 2; ++ks) {
                u16x8 a[4], bb[4];
                #pragma unroll
                for (int mi = 0; mi < 4; ++mi) {
                    const int row = wm * 64 + mi * 16 + i;
                    a[mi] = *(const u16x8*)&xb[row * 64 + (((ks * 4 + g) ^ (row & 7)) << 3)];
                }
                #pragma unroll
                for (int nj = 0; nj < 4; ++nj) {
                    const int row = wn * 64 + nj * 16 + i;
                    bb[nj] = *(const u16x8*)&wb[row * 64 + (((ks * 4 + g) ^ (row & 7)) << 3)];
                }
                #pragma unroll
                for (int mi = 0; mi < 4; ++mi)
                    #pragma unroll
                    for (int nj = 0; nj < 4; ++nj)
                        acc[mi][nj] = mfma16(a[mi], bb[nj], acc[mi][nj]);
            }
            __builtin_amdgcn_sched_barrier(0);
            __builtin_amdgcn_s_barrier();
            if (c + 2 < 4) {
                stage(c & 1, (c + 2) << 6);
                asm volatile("s_waitcnt vmcnt(8)" ::: "memory");
            } else {
                asm volatile("s_waitcnt vmcnt(0)" ::: "memory");
            }
            __builtin_amdgcn_s_barrier();
        }

        float* lf = (float*)lds;
        const int pxq = tid >> 2, segq = tid & 3;

        #pragma unroll
        for (int h = 0; h < 2; ++h) {
            if (wm == h) {
                #pragma unroll
                for (int nj = 0; nj < 4; ++nj) {
                    const int ocl = wn * 64 + nj * 16 + i;
                    const float bv = val_b[oc0 + ocl];
                    #pragma unroll
                    for (int mi = 0; mi < 4; ++mi)
                        #pragma unroll
                        for (int r = 0; r < 4; ++r)
                            lf[ocl * 66 + mi * 16 + g * 4 + r] = acc[mi][nj][r] + bv;
                }
            }
            __syncthreads();
            const int pxg0 = px0 + h * 64;
            const size_t nb = ((size_t)(b * P_ + pxg0 + pxq)) * 256 + oc0 + segq * 32;
            #pragma unroll
            for (int t2 = 0; t2 < 4; ++t2) {
                u16x8 o8;
                #pragma unroll
                for (int jj = 0; jj < 8; ++jj)
                    o8[jj] = f2bf(lf[(segq * 32 + t2 * 8 + jj) * 66 + pxq]);
                *(u16x8*)&value_bf[nb + t2 * 8] = o8;
            }
            __syncthreads();
        }
    }
}

// ---------------------------------------------------------------------------
// Double-buffered 128x128-tile NHWC bf16 GEMM, BK=64, counted vmcnt pipeline.
// modes: 1 +bias+relu -> bf16 NHWC(outB);
//        4 +bias +resid f32 NCHW -> bf16 NHWC(outB);
//        6 +bias +resid bf16 NHWC -> f32 NCHW(outA).
// ---------------------------------------------------------------------------
__global__ __launch_bounds__(256, 2) void gemm_dbuf(
    const u16* __restrict__ X, const u16* __restrict__ W,
    const float* __restrict__ bias, const void* __restrict__ resid,
    void* __restrict__ outA, u16* __restrict__ outB,
    const int KTOT, const int OC, const int mode) {
    const int px0 = blockIdx.x * 128, oc0 = blockIdx.y * 128, b = blockIdx.z;
    const int tid = threadIdx.x, w = tid >> 6, lane = tid & 63, g = lane >> 4, i = lane & 15;
    const int wm = w & 1, wn = w >> 1;
    __shared__ u16 lds[32768];           // 64 KB
    u16* xs = lds;
    u16* wsL = lds + 16384;

    const int srcC = (lane & 7) ^ ((lane >> 3) & 7);

    f32x4 acc[4][4];
    #pragma unroll
    for (int mi = 0; mi < 4; ++mi)
        #pragma unroll
        for (int nj = 0; nj < 4; ++nj) acc[mi][nj] = (f32x4){0.f, 0.f, 0.f, 0.f};

    const int NC = KTOT >> 6;

    auto stage = [&](int buf, int kc) {
        #pragma unroll
        for (int t = 0; t < 4; ++t) {
            const int j = w * 4 + t;
            const int row = j * 8 + (lane >> 3);
            gload16(X + (size_t)(b * P_ + px0 + row) * KTOT + kc + (srcC << 3),
                    &xs[buf * 8192 + j * 512]);
        }
        #pragma unroll
        for (int t = 0; t < 4; ++t) {
            const int j = w * 4 + t;
            const int row = j * 8 + (lane >> 3);
            gload16(W + (size_t)(oc0 + row) * KTOT + kc + (srcC << 3),
                    &wsL[buf * 8192 + j * 512]);
        }
    };

    stage(0, 0);
    stage(1, 64);
    asm volatile("s_waitcnt vmcnt(8)" ::: "memory");
    __builtin_amdgcn_s_barrier();

    for (int c = 0; c < NC; ++c) {
        const u16* xb = &xs[(c & 1) * 8192];
        const u16* wb = &wsL[(c & 1) * 8192];
        #pragma unroll
        for (int ks = 0; ks < 2; ++ks) {
            u16x8 a[4], bb[4];
            #pragma unroll
            for (int mi = 0; mi < 4; ++mi) {
                const int row = wm * 64 + mi * 16 + i;
                a[mi] = *(const u16x8*)&xb[row * 64 + (((ks * 4 + g) ^ (row & 7)) << 3)];
            }
            #pragma unroll
            for (int nj = 0; nj < 4; ++nj) {
                const int row = wn * 64 + nj * 16 + i;
                bb[nj] = *(const u16x8*)&wb[row * 64 + (((ks * 4 + g) ^ (row & 7)) << 3)];
            }
            #pragma unroll
            for (int mi = 0; mi < 4; ++mi)
                #pragma unroll
                for (int nj = 0; nj < 4; ++nj)
                    acc[mi][nj] = mfma16(a[mi], bb[nj], acc[mi][nj]);
        }
        __builtin_amdgcn_sched_barrier(0);
        __builtin_amdgcn_s_barrier();
        if (c + 2 < NC) {
            stage(c & 1, (c + 2) << 6);
            asm volatile("s_waitcnt vmcnt(8)" ::: "memory");
        } else {
            asm volatile("s_waitcnt vmcnt(0)" ::: "memory");
        }
        __builtin_amdgcn_s_barrier();
    }

    float* lf = (float*)lds;
    const int pxq = tid >> 2, segq = tid & 3;
    const int oclh = tid >> 1, shh = (tid & 1) * 32;

    #pragma unroll
    for (int h = 0; h < 2; ++h) {
        if (wm == h) {
            #pragma unroll
            for (int nj = 0; nj < 4; ++nj) {
                const int ocl = wn * 64 + nj * 16 + i;
                const float bv = bias[oc0 + ocl];
                #pragma unroll
                for (int mi = 0; mi < 4; ++mi)
                    #pragma unroll
                    for (int r = 0; r < 4; ++r)
                        lf[ocl * 66 + mi * 16 + g * 4 + r] = acc[mi][nj][r] + bv;
            }
        }
        __syncthreads();
        const int pxg0 = px0 + h * 64;

        if (mode == 4) {                 // += f_orig (f32 NCHW), coalesced
            const float* rf = (const float*)resid;
            const size_t rb = ((size_t)b * 256 + oc0 + oclh) * P_ + pxg0 + shh;
            #pragma unroll
            for (int q = 0; q < 8; ++q) {
                const float4 r4 = *(const float4*)&rf[rb + q * 4];
                lf[oclh * 66 + shh + q * 4 + 0] += r4.x;
                lf[oclh * 66 + shh + q * 4 + 1] += r4.y;
                lf[oclh * 66 + shh + q * 4 + 2] += r4.z;
                lf[oclh * 66 + shh + q * 4 + 3] += r4.w;
            }
            __syncthreads();
        }
        if (mode == 6) {                 // += out2 (bf16 NHWC)
            const u16* rn = (const u16*)resid;
            const size_t nb = ((size_t)(b * P_ + pxg0 + pxq)) * 256 + oc0 + segq * 32;
            #pragma unroll
            for (int t2 = 0; t2 < 4; ++t2) {
                const u16x8 r8 = *(const u16x8*)&rn[nb + t2 * 8];
                #pragma unroll
                for (int jj = 0; jj < 8; ++jj)
                    lf[(segq * 32 + t2 * 8 + jj) * 66 + pxq] += bf2f(r8[jj]);
            }
            __syncthreads();
        }

        if (mode <= 1 || mode == 4) {    // bf16 NHWC store, 16B/lane
            const size_t nb = ((size_t)(b * P_ + pxg0 + pxq)) * OC + oc0 + segq * 32;
            #pragma unroll
            for (int t2 = 0; t2 < 4; ++t2) {
                u16x8 o8;
                #pragma unroll
                for (int jj = 0; jj < 8; ++jj) {
                    float v = lf[(segq * 32 + t2 * 8 + jj) * 66 + pxq];
                    if (mode == 1) v = fmaxf(v, 0.f);
                    o8[jj] = f2bf(v);
                }
                *(u16x8*)&outB[nb + t2 * 8] = o8;
            }
        }
        if (mode == 6) {                 // f32 NCHW store
            float* of = (float*)outA;
            const size_t cb = ((size_t)b * 256 + oc0 + oclh) * P_ + pxg0 + shh;
            #pragma unroll
            for (int q = 0; q < 8; ++q) {
                float4 o;
                o.x = lf[oclh * 66 + shh + q * 4 + 0];
                o.y = lf[oclh * 66 + shh + q * 4 + 1];
                o.z = lf[oclh * 66 + shh + q * 4 + 2];
                o.w = lf[oclh * 66 + shh + q * 4 + 3];
                *(float4*)&of[cb + q * 4] = o;
            }
        }
        __syncthreads();
    }
}

// ---------------------------------------------------------------------------
// softmax over K + bilinear grid-sample + weighted sum (unchanged).
// ---------------------------------------------------------------------------
__global__ __launch_bounds__(256) void sample_attend_bf(
    const u16* __restrict__ value, const u16* __restrict__ conv,
    u16* __restrict__ out1) {
    const int y = blockIdx.x, m = blockIdx.y, b = blockIdx.z;
    const int tid = threadIdx.x, x = tid >> 2, gq = tid & 3;
    const int w = tid >> 6, lane = tid & 63;
    const int wlo = max(0, y - 3), whi = min(63, y + 4);
    const int nchunks = (whi - wlo + 1) * 256;
    __shared__ u16 vlds[8 * 64 * 32];

    const u16* vbase = value + ((size_t)b * P_) * 256 + m * 32;
    for (int it = w; it * 64 < nchunks; it += 4) {
        const int cid = it * 64 + lane;
        const int r = cid >> 8, px = (cid >> 2) & 63, cc = cid & 3;
        gload16(vbase + ((size_t)((wlo + r) * 64 + px)) * 256 + cc * 8,
                &vlds[it * 512]);
    }

    const size_t prow = (size_t)(b * P_ + y * 64 + x);
    const u16x8 ov = *(const u16x8*)&conv[prow * 96 + m * 8];
    const u16x4 av = *(const u16x4*)&conv[prow * 96 + 64 + m * 4];
    float a[4];
    #pragma unroll
    for (int k = 0; k < 4; ++k) a[k] = bf2f(av[k]);
    const float mx = fmaxf(fmaxf(a[0], a[1]), fmaxf(a[2], a[3]));
    float s = 0.f;
    #pragma unroll
    for (int k = 0; k < 4; ++k) { a[k] = __expf(a[k] - mx); s += a[k]; }
    const float inv = 1.f / s;

    __syncthreads();

    float acc[8];
    #pragma unroll
    for (int j = 0; j < 8; ++j) acc[j] = 0.f;

    #pragma unroll
    for (int k = 0; k < 4; ++k) {
        const float offx = bf2f(ov[2 * k]), offy = bf2f(ov[2 * k + 1]);
        const float px = (float)(63 - x) + offx;
        const float py = (float)y + offy;
        const float x0f = floorf(px), y0f = floorf(py);
        const int xi0 = (int)x0f, yi0 = (int)y0f;
        const float wx = px - x0f, wy = py - y0f;
        const int xi1 = xi0 + 1, yi1 = yi0 + 1;
        const bool vx0 = (xi0 >= 0) & (xi0 <= 63), vx1 = (xi1 >= 0) & (xi1 <= 63);
        const bool vy0 = (yi0 >= 0) & (yi0 <= 63), vy1 = (yi1 >= 0) & (yi1 <= 63);
        const int cx0 = min(max(xi0, 0), 63), cx1 = min(max(xi1, 0), 63);
        const int cy0 = min(max(yi0, 0), 63), cy1 = min(max(yi1, 0), 63);
        const float ak = a[k] * inv;
        const float c00 = ak * (1.f - wx) * (1.f - wy) * ((vx0 & vy0) ? 1.f : 0.f);
        const float c01 = ak * wx * (1.f - wy) * ((vx1 & vy0) ? 1.f : 0.f);
        const float c10 = ak * (1.f - wx) * wy * ((vx0 & vy1) ? 1.f : 0.f);
        const float c11 = ak * wx * wy * ((vx1 & vy1) ? 1.f : 0.f);
        u16x8 v00, v01, v10, v11;
        const bool inWin = (cy0 >= wlo) & (cy1 <= whi);
        if (inWin) {
            const int r0 = (cy0 - wlo) * 64, r1 = (cy1 - wlo) * 64;
            v00 = *(const u16x8*)&vlds[(r0 + cx0) * 32 + gq * 8];
            v01 = *(const u16x8*)&vlds[(r0 + cx1) * 32 + gq * 8];
            v10 = *(const u16x8*)&vlds[(r1 + cx0) * 32 + gq * 8];
            v11 = *(const u16x8*)&vlds[(r1 + cx1) * 32 + gq * 8];
        } else {
            const u16* vb = vbase + gq * 8;
            v00 = *(const u16x8*)&vb[(size_t)(cy0 * 64 + cx0) * 256];
            v01 = *(const u16x8*)&vb[(size_t)(cy0 * 64 + cx1) * 256];
            v10 = *(const u16x8*)&vb[(size_t)(cy1 * 64 + cx0) * 256];
            v11 = *(const u16x8*)&vb[(size_t)(cy1 * 64 + cx1) * 256];
        }
        #pragma unroll
        for (int j = 0; j < 8; ++j)
            acc[j] += c00 * bf2f(v00[j]) + c01 * bf2f(v01[j])
                    + c10 * bf2f(v10[j]) + c11 * bf2f(v11[j]);
    }
    u16x8 o;
    #pragma unroll
    for (int j = 0; j < 8; ++j) o[j] = f2bf(acc[j]);
    *(u16x8*)&out1[prow * 256 + m * 32 + gq * 8] = o;
}

// ---------------------------------------------------------------------------
extern "C" void kernel_launch(void* const* d_in, const int* in_sizes, int n_in,
                              void* d_out, int out_size, void* d_ws, size_t ws_size,
                              hipStream_t stream) {
    const float* f_recalib = (const float*)d_in[0];
    const float* f_orig    = (const float*)d_in[1];
    const float* offset_w  = (const float*)d_in[2];
    const float* offset_b  = (const float*)d_in[3];
    const float* attn_w    = (const float*)d_in[4];
    const float* attn_b    = (const float*)d_in[5];
    const float* value_w   = (const float*)d_in[6];
    const float* value_b   = (const float*)d_in[7];
    const float* proj_w    = (const float*)d_in[8];
    const float* proj_b    = (const float*)d_in[9];
    const float* mlp_w1    = (const float*)d_in[10];
    const float* mlp_b1    = (const float*)d_in[11];
    const float* mlp_w2    = (const float*)d_in[12];
    const float* mlp_b2    = (const float*)d_in[13];
    float* out = (float*)d_out;

    u16* wsb       = (u16*)d_ws;
    u16* x_pad     = wsb;                  // 8,921,088 u16 (17.8 MB)
    u16* convout   = wsb + 8921088;        // 3,145,728 (6 MB)
    u16* value_bf  = wsb + 12066816;       // 8,388,608 (16 MB)
    u16* out1_bf   = wsb + 20455424;       // 8,388,608 (16 MB)
    u16* wbf       = wsb + 28844032;       // 614,400 (1.2 MB) -> 59 MB total
    u16* out2_bf   = x_pad;                // alias: x_pad dead after conv+value
    u16* h_bf      = wsb + 8921088;        // alias convout+value+out1 (dead), 32 MB

    u16* wconv = wbf;
    u16* wval  = wbf + 221184;
    u16* wproj = wbf + 286720;
    u16* wmlp1 = wbf + 352256;
    u16* wmlp2 = wbf + 483328;

    // 1. fused NCHW->NHWC-pad conversion + weight prep
    to_nhwc_pad<<<dim3(139, 4, 8), 256, 0, stream>>>(
        f_recalib, x_pad, offset_w, attn_w, value_w, proj_w, mlp_w1, mlp_w2, wbf);
    // 2. conv3x3 + value GEMM in one dispatch (even/odd block split)
    conv_value<<<dim3(1024), 256, 0, stream>>>(
        x_pad, wconv, wval, offset_b, attn_b, value_b, convout, value_bf);
    // 3. softmax + grid sample + weighted sum
    sample_attend_bf<<<dim3(64, 8, 8), 256, 0, stream>>>(value_bf, convout, out1_bf);
    // 4. proj + f_orig -> out2_bf (bf16 NHWC only)
    gemm_dbuf<<<dim3(32, 2, 8), 256, 0, stream>>>(out1_bf, wproj, proj_b, f_orig,
                                                  nullptr, out2_bf, 256, 256, 4);
    // 5. h = relu(mlp1(out2))
    gemm_dbuf<<<dim3(32, 4, 8), 256, 0, stream>>>(out2_bf, wmlp1, mlp_b1, nullptr,
                                                  nullptr, h_bf, 256, 512, 1);
    // 6. out = mlp2(h) + out2 (NHWC resid) -> f32 NCHW
    gemm_dbuf<<<dim3(32, 2, 8), 256, 0, stream>>>(h_bf, wmlp2, mlp_b2, out2_bf,
                                                  out, nullptr, 512, 256, 6);
}

// Round 18
// 141.409 us; speedup vs baseline: 1.0162x; 1.0162x over previous
//
#include <hip/hip_runtime.h>
#include <cstddef>

#define P_ 4096
#define PW_ 66   // padded width/height

using u16 = unsigned short;
typedef float  f32x4  __attribute__((ext_vector_type(4)));
typedef u16    u16x8  __attribute__((ext_vector_type(8)));
typedef u16    u16x4  __attribute__((ext_vector_type(4)));
typedef __bf16 bf16x8 __attribute__((ext_vector_type(8)));

#define DEVINL __device__ __forceinline__

DEVINL u16 f2bf(float f) {
    union { float f; unsigned u; } v; v.f = f;
    unsigned r = v.u + 0x7fffu + ((v.u >> 16) & 1u);
    return (u16)(r >> 16);
}
DEVINL float bf2f(u16 h) {
    union { unsigned u; float f; } v; v.u = ((unsigned)h) << 16;
    return v.f;
}

DEVINL f32x4 mfma16(u16x8 a, u16x8 b, f32x4 c) {
    return __builtin_amdgcn_mfma_f32_16x16x32_bf16(
        __builtin_bit_cast(bf16x8, a), __builtin_bit_cast(bf16x8, b), c, 0, 0, 0);
}

DEVINL void gload16(const u16* src, const u16* lds_dst) {
    __builtin_amdgcn_global_load_lds(
        (const __attribute__((address_space(1))) void*)src,
        (__attribute__((address_space(3))) void*)lds_dst, 16, 0, 0);
}

// ---------------------------------------------------------------------------
// NCHW fp32 -> padded NHWC bf16 (+ pad-ring zeroing by y==0 blocks).
// blockIdx.x >= 64: weight-prep blocks (all weights -> bf16; conv weights
// reordered to [tap][96][256]). grid (64+75, 4, 8), 256 thr.
// ---------------------------------------------------------------------------
__global__ __launch_bounds__(256) void to_nhwc_pad(
    const float* __restrict__ in, u16* __restrict__ xp,
    const float* __restrict__ off_w, const float* __restrict__ attn_w,
    const float* __restrict__ val_w, const float* __restrict__ proj_w,
    const float* __restrict__ w1, const float* __restrict__ w2,
    u16* __restrict__ wbf) {
    const int bx = blockIdx.x, c0 = blockIdx.y * 64, b = blockIdx.z;
    const int t = threadIdx.x;

    if (bx >= 64) {   // weight prep: 2400 virtual blocks x 256 elems
        const int idx = ((bx - 64) * 32 + blockIdx.y * 8 + b) * 256 + t;
        if (idx >= 614400) return;
        float v;
        if (idx < 221184) {
            int tap = idx / 24576, rem = idx - tap * 24576, oc = rem >> 8, ic = rem & 255;
            v = (oc < 64) ? off_w[(size_t)(oc * 256 + ic) * 9 + tap]
                          : attn_w[(size_t)((oc - 64) * 256 + ic) * 9 + tap];
        } else if (idx < 286720) v = val_w[idx - 221184];
        else if (idx < 352256)   v = proj_w[idx - 286720];
        else if (idx < 483328)   v = w1[idx - 352256];
        else                     v = w2[idx - 483328];
        wbf[idx] = f2bf(v);
        return;
    }

    const int y = bx;
    __shared__ u16 ts[64 * 72];
    const int cl = t >> 4, xq = t & 15;

    if (y == 0) {   // zero pad ring for this channel range
        const u16x8 z = (u16x8){0, 0, 0, 0, 0, 0, 0, 0};
        for (int q = t; q < 2080; q += 256) {
            const int p = q >> 3, c8 = q & 7;
            int row, col;
            if (p < 66)       { row = 0;  col = p; }
            else if (p < 132) { row = 65; col = p - 66; }
            else { const int q2 = p - 132; row = 1 + (q2 >> 1); col = (q2 & 1) * 65; }
            *(u16x8*)&xp[((size_t)(b * PW_ + row) * PW_ + col) * 256 + c0 + c8 * 8] = z;
        }
    }

    #pragma unroll
    for (int r = 0; r < 4; ++r) {
        const int c = r * 16 + cl;
        const float4 v = *(const float4*)&in[((size_t)(b * 256 + c0 + c)) * P_ + y * 64 + xq * 4];
        ts[(xq * 4 + 0) * 72 + c] = f2bf(v.x);
        ts[(xq * 4 + 1) * 72 + c] = f2bf(v.y);
        ts[(xq * 4 + 2) * 72 + c] = f2bf(v.z);
        ts[(xq * 4 + 3) * 72 + c] = f2bf(v.w);
    }
    __syncthreads();
    const int px = t >> 2, seg = t & 3;
    u16x8 o0, o1;
    #pragma unroll
    for (int j = 0; j < 8; ++j) {
        o0[j] = ts[px * 72 + seg * 16 + j];
        o1[j] = ts[px * 72 + seg * 16 + 8 + j];
    }
    const size_t base = ((size_t)(b * PW_ + y + 1) * PW_ + 1 + px) * 256 + c0 + seg * 16;
    *(u16x8*)&xp[base]     = o0;
    *(u16x8*)&xp[base + 8] = o1;
}

// ---------------------------------------------------------------------------
// conv3x3 as 9 shifted full-GEMMs, double-buffered counted-vmcnt pipeline.
// 18 chunks: c -> tap=c>>1, kc=(c&1)*128. LDS 2 x (A 16KB + W 24KB) = 80KB
// -> 2 blocks/CU. 10 loads/thread/stage; vmcnt(10) mid-loop.
// grid (64 y, 8 b), 256 thr (4 waves: wm px-half 32, wn oc-half 48).
// ---------------------------------------------------------------------------
__global__ __launch_bounds__(256, 2) void conv3x3_mfma(
    const u16* __restrict__ xp, const u16* __restrict__ wconv,
    const float* __restrict__ off_b, const float* __restrict__ attn_b,
    u16* __restrict__ convout) {
    const int y = blockIdx.x, b = blockIdx.y;
    const int tid = threadIdx.x, w = tid >> 6, lane = tid & 63, g = lane >> 4, i = lane & 15;
    const int wm = w & 1, wn = w >> 1;
    const int srow = lane >> 4, sc = lane & 15;
    __shared__ u16 lds[40960];           // 80 KB: A[2][8192] + W[2][12288]

    f32x4 acc[2][3];
    #pragma unroll
    for (int mi = 0; mi < 2; ++mi)
        #pragma unroll
        for (int nj = 0; nj < 3; ++nj) acc[mi][nj] = (f32x4){0.f, 0.f, 0.f, 0.f};

    auto stage = [&](int buf, int c) {
        const int tap = c >> 1, kc = (c & 1) * 128;
        const int dy = tap / 3, dx = tap % 3;
        const u16* xrow = xp + ((size_t)(b * PW_ + y + dy) * PW_ + dx) * 256;
        const u16* wt = wconv + (size_t)(tap * 96) * 256;
        u16* bufA = &lds[buf * 8192];
        u16* bufW = &lds[16384 + buf * 12288];
        #pragma unroll
        for (int t = 0; t < 4; ++t) {
            const int j = w * 4 + t;
            const int row = j * 4 + srow;              // x 0..63
            const int cs = sc ^ (row & 7);
            gload16(xrow + (size_t)row * 256 + kc + (cs << 3), &bufA[j * 512]);
        }
        #pragma unroll
        for (int t = 0; t < 6; ++t) {
            const int j = w * 6 + t;
            const int row = j * 4 + srow;              // oc 0..95
            const int cs = sc ^ (row & 7);
            gload16(wt + (size_t)row * 256 + kc + (cs << 3), &bufW[j * 512]);
        }
    };

    stage(0, 0);
    stage(1, 1);
    asm volatile("s_waitcnt vmcnt(10)" ::: "memory");   // chunk 0 landed
    __builtin_amdgcn_s_barrier();

    for (int c = 0; c < 18; ++c) {
        const u16* bufA = &lds[(c & 1) * 8192];
        const u16* bufW = &lds[16384 + (c & 1) * 12288];
        #pragma unroll
        for (int ks = 0; ks < 4; ++ks) {
            u16x8 a[2], bb[3];
            #pragma unroll
            for (int mi = 0; mi < 2; ++mi) {
                const int pr = wm * 32 + mi * 16 + i;
                a[mi] = *(const u16x8*)&bufA[pr * 128 + (((ks * 4 + g) ^ (pr & 7)) << 3)];
            }
            #pragma unroll
            for (int nj = 0; nj < 3; ++nj) {
                const int ocr = wn * 48 + nj * 16 + i;
                bb[nj] = *(const u16x8*)&bufW[ocr * 128 + (((ks * 4 + g) ^ (ocr & 7)) << 3)];
            }
            #pragma unroll
            for (int mi = 0; mi < 2; ++mi)
                #pragma unroll
                for (int nj = 0; nj < 3; ++nj)
                    acc[mi][nj] = mfma16(a[mi], bb[nj], acc[mi][nj]);
        }
        __builtin_amdgcn_sched_barrier(0);
        __builtin_amdgcn_s_barrier();            // all waves done reading buf c&1
        if (c + 2 < 18) {
            stage(c & 1, c + 2);
            asm volatile("s_waitcnt vmcnt(10)" ::: "memory");  // chunk c+1 landed
        } else {
            asm volatile("s_waitcnt vmcnt(0)" ::: "memory");
        }
        __builtin_amdgcn_s_barrier();
    }

    #pragma unroll
    for (int mi = 0; mi < 2; ++mi) {
        const int x0 = wm * 32 + mi * 16 + g * 4;
        #pragma unroll
        for (int nj = 0; nj < 3; ++nj) {
            const int oc = wn * 48 + nj * 16 + i;
            const float bv = (oc < 64) ? off_b[oc] : attn_b[oc - 64];
            #pragma unroll
            for (int r = 0; r < 4; ++r)
                convout[((size_t)(b * P_ + y * 64 + x0 + r)) * 96 + oc] =
                    f2bf(acc[mi][nj][r] + bv);
        }
    }
}

// ---------------------------------------------------------------------------
// Double-buffered 128x128-tile NHWC bf16 GEMM, BK=64, counted vmcnt pipeline.
// padded=1: X is the 66x66 padded image (KTOT must be 256).
// modes: 0 +bias -> bf16 NHWC(outB); 1 +bias+relu -> bf16 NHWC(outB);
//        4 +bias +resid f32 NCHW -> bf16 NHWC(outB);
//        6 +bias +resid bf16 NHWC -> f32 NCHW(outA).
// ---------------------------------------------------------------------------
__global__ __launch_bounds__(256, 2) void gemm_dbuf(
    const u16* __restrict__ X, const u16* __restrict__ W,
    const float* __restrict__ bias, const void* __restrict__ resid,
    void* __restrict__ outA, u16* __restrict__ outB,
    const int KTOT, const int OC, const int mode, const int padded) {
    const int px0 = blockIdx.x * 128, oc0 = blockIdx.y * 128, b = blockIdx.z;
    const int tid = threadIdx.x, w = tid >> 6, lane = tid & 63, g = lane >> 4, i = lane & 15;
    const int wm = w & 1, wn = w >> 1;
    __shared__ u16 lds[32768];           // 64 KB
    u16* xs = lds;
    u16* wsL = lds + 16384;

    const int srcC = (lane & 7) ^ ((lane >> 3) & 7);

    f32x4 acc[4][4];
    #pragma unroll
    for (int mi = 0; mi < 4; ++mi)
        #pragma unroll
        for (int nj = 0; nj < 4; ++nj) acc[mi][nj] = (f32x4){0.f, 0.f, 0.f, 0.f};

    const int NC = KTOT >> 6;

    auto stage = [&](int buf, int kc) {
        #pragma unroll
        for (int t = 0; t < 4; ++t) {
            const int j = w * 4 + t;
            const int row = j * 8 + (lane >> 3);
            const u16* sx;
            if (padded) {
                const int pxg = px0 + row;
                sx = X + ((size_t)(b * PW_ + (pxg >> 6) + 1) * PW_ + (pxg & 63) + 1) * 256
                       + kc + (srcC << 3);
            } else {
                sx = X + (size_t)(b * P_ + px0 + row) * KTOT + kc + (srcC << 3);
            }
            gload16(sx, &xs[buf * 8192 + j * 512]);
        }
        #pragma unroll
        for (int t = 0; t < 4; ++t) {
            const int j = w * 4 + t;
            const int row = j * 8 + (lane >> 3);
            gload16(W + (size_t)(oc0 + row) * KTOT + kc + (srcC << 3),
                    &wsL[buf * 8192 + j * 512]);
        }
    };

    stage(0, 0);
    stage(1, 64);
    asm volatile("s_waitcnt vmcnt(8)" ::: "memory");
    __builtin_amdgcn_s_barrier();

    for (int c = 0; c < NC; ++c) {
        const u16* xb = &xs[(c & 1) * 8192];
        const u16* wb = &wsL[(c & 1) * 8192];
        #pragma unroll
        for (int ks = 0; ks < 2; ++ks) {
            u16x8 a[4], bb[4];
            #pragma unroll
            for (int mi = 0; mi < 4; ++mi) {
                const int row = wm * 64 + mi * 16 + i;
                a[mi] = *(const u16x8*)&xb[row * 64 + (((ks * 4 + g) ^ (row & 7)) << 3)];
            }
            #pragma unroll
            for (int nj = 0; nj < 4; ++nj) {
                const int row = wn * 64 + nj * 16 + i;
                bb[nj] = *(const u16x8*)&wb[row * 64 + (((ks * 4 + g) ^ (row & 7)) << 3)];
            }
            #pragma unroll
            for (int mi = 0; mi < 4; ++mi)
                #pragma unroll
                for (int nj = 0; nj < 4; ++nj)
                    acc[mi][nj] = mfma16(a[mi], bb[nj], acc[mi][nj]);
        }
        __builtin_amdgcn_sched_barrier(0);
        __builtin_amdgcn_s_barrier();
        if (c + 2 < NC) {
            stage(c & 1, (c + 2) << 6);
            asm volatile("s_waitcnt vmcnt(8)" ::: "memory");
        } else {
            asm volatile("s_waitcnt vmcnt(0)" ::: "memory");
        }
        __builtin_amdgcn_s_barrier();
    }

    float* lf = (float*)lds;
    const int pxq = tid >> 2, segq = tid & 3;
    const int oclh = tid >> 1, shh = (tid & 1) * 32;

    #pragma unroll
    for (int h = 0; h < 2; ++h) {
        if (wm == h) {
            #pragma unroll
            for (int nj = 0; nj < 4; ++nj) {
                const int ocl = wn * 64 + nj * 16 + i;
                const float bv = bias[oc0 + ocl];
                #pragma unroll
                for (int mi = 0; mi < 4; ++mi)
                    #pragma unroll
                    for (int r = 0; r < 4; ++r)
                        lf[ocl * 66 + mi * 16 + g * 4 + r] = acc[mi][nj][r] + bv;
            }
        }
        __syncthreads();
        const int pxg0 = px0 + h * 64;

        if (mode == 4) {                 // += f_orig (f32 NCHW), coalesced
            const float* rf = (const float*)resid;
            const size_t rb = ((size_t)b * 256 + oc0 + oclh) * P_ + pxg0 + shh;
            #pragma unroll
            for (int q = 0; q < 8; ++q) {
                const float4 r4 = *(const float4*)&rf[rb + q * 4];
                lf[oclh * 66 + shh + q * 4 + 0] += r4.x;
                lf[oclh * 66 + shh + q * 4 + 1] += r4.y;
                lf[oclh * 66 + shh + q * 4 + 2] += r4.z;
                lf[oclh * 66 + shh + q * 4 + 3] += r4.w;
            }
            __syncthreads();
        }
        if (mode == 6) {                 // += out2 (bf16 NHWC)
            const u16* rn = (const u16*)resid;
            const size_t nb = ((size_t)(b * P_ + pxg0 + pxq)) * 256 + oc0 + segq * 32;
            #pragma unroll
            for (int t2 = 0; t2 < 4; ++t2) {
                const u16x8 r8 = *(const u16x8*)&rn[nb + t2 * 8];
                #pragma unroll
                for (int jj = 0; jj < 8; ++jj)
                    lf[(segq * 32 + t2 * 8 + jj) * 66 + pxq] += bf2f(r8[jj]);
            }
            __syncthreads();
        }

        if (mode <= 1 || mode == 4) {    // bf16 NHWC store, 16B/lane
            const size_t nb = ((size_t)(b * P_ + pxg0 + pxq)) * OC + oc0 + segq * 32;
            #pragma unroll
            for (int t2 = 0; t2 < 4; ++t2) {
                u16x8 o8;
                #pragma unroll
                for (int jj = 0; jj < 8; ++jj) {
                    float v = lf[(segq * 32 + t2 * 8 + jj) * 66 + pxq];
                    if (mode == 1) v = fmaxf(v, 0.f);
                    o8[jj] = f2bf(v);
                }
                *(u16x8*)&outB[nb + t2 * 8] = o8;
            }
        }
        if (mode == 6) {                 // f32 NCHW store
            float* of = (float*)outA;
            const size_t cb = ((size_t)b * 256 + oc0 + oclh) * P_ + pxg0 + shh;
            #pragma unroll
            for (int q = 0; q < 8; ++q) {
                float4 o;
                o.x = lf[oclh * 66 + shh + q * 4 + 0];
                o.y = lf[oclh * 66 + shh + q * 4 + 1];
                o.z = lf[oclh * 66 + shh + q * 4 + 2];
                o.w = lf[oclh * 66 + shh + q * 4 + 3];
                *(float4*)&of[cb + q * 4] = o;
            }
        }
        __syncthreads();
    }
}

// ---------------------------------------------------------------------------
// softmax over K + bilinear grid-sample + weighted sum (unchanged).
// ---------------------------------------------------------------------------
__global__ __launch_bounds__(256) void sample_attend_bf(
    const u16* __restrict__ value, const u16* __restrict__ conv,
    u16* __restrict__ out1) {
    const int y = blockIdx.x, m = blockIdx.y, b = blockIdx.z;
    const int tid = threadIdx.x, x = tid >> 2, gq = tid & 3;
    const int w = tid >> 6, lane = tid & 63;
    const int wlo = max(0, y - 3), whi = min(63, y + 4);
    const int nchunks = (whi - wlo + 1) * 256;
    __shared__ u16 vlds[8 * 64 * 32];

    const u16* vbase = value + ((size_t)b * P_) * 256 + m * 32;
    for (int it = w; it * 64 < nchunks; it += 4) {
        const int cid = it * 64 + lane;
        const int r = cid >> 8, px = (cid >> 2) & 63, cc = cid & 3;
        gload16(vbase + ((size_t)((wlo + r) * 64 + px)) * 256 + cc * 8,
                &vlds[it * 512]);
    }

    const size_t prow = (size_t)(b * P_ + y * 64 + x);
    const u16x8 ov = *(const u16x8*)&conv[prow * 96 + m * 8];
    const u16x4 av = *(const u16x4*)&conv[prow * 96 + 64 + m * 4];
    float a[4];
    #pragma unroll
    for (int k = 0; k < 4; ++k) a[k] = bf2f(av[k]);
    const float mx = fmaxf(fmaxf(a[0], a[1]), fmaxf(a[2], a[3]));
    float s = 0.f;
    #pragma unroll
    for (int k = 0; k < 4; ++k) { a[k] = __expf(a[k] - mx); s += a[k]; }
    const float inv = 1.f / s;

    __syncthreads();

    float acc[8];
    #pragma unroll
    for (int j = 0; j < 8; ++j) acc[j] = 0.f;

    #pragma unroll
    for (int k = 0; k < 4; ++k) {
        const float offx = bf2f(ov[2 * k]), offy = bf2f(ov[2 * k + 1]);
        const float px = (float)(63 - x) + offx;
        const float py = (float)y + offy;
        const float x0f = floorf(px), y0f = floorf(py);
        const int xi0 = (int)x0f, yi0 = (int)y0f;
        const float wx = px - x0f, wy = py - y0f;
        const int xi1 = xi0 + 1, yi1 = yi0 + 1;
        const bool vx0 = (xi0 >= 0) & (xi0 <= 63), vx1 = (xi1 >= 0) & (xi1 <= 63);
        const bool vy0 = (yi0 >= 0) & (yi0 <= 63), vy1 = (yi1 >= 0) & (yi1 <= 63);
        const int cx0 = min(max(xi0, 0), 63), cx1 = min(max(xi1, 0), 63);
        const int cy0 = min(max(yi0, 0), 63), cy1 = min(max(yi1, 0), 63);
        const float ak = a[k] * inv;
        const float c00 = ak * (1.f - wx) * (1.f - wy) * ((vx0 & vy0) ? 1.f : 0.f);
        const float c01 = ak * wx * (1.f - wy) * ((vx1 & vy0) ? 1.f : 0.f);
        const float c10 = ak * (1.f - wx) * wy * ((vx0 & vy1) ? 1.f : 0.f);
        const float c11 = ak * wx * wy * ((vx1 & vy1) ? 1.f : 0.f);
        u16x8 v00, v01, v10, v11;
        const bool inWin = (cy0 >= wlo) & (cy1 <= whi);
        if (inWin) {
            const int r0 = (cy0 - wlo) * 64, r1 = (cy1 - wlo) * 64;
            v00 = *(const u16x8*)&vlds[(r0 + cx0) * 32 + gq * 8];
            v01 = *(const u16x8*)&vlds[(r0 + cx1) * 32 + gq * 8];
            v10 = *(const u16x8*)&vlds[(r1 + cx0) * 32 + gq * 8];
            v11 = *(const u16x8*)&vlds[(r1 + cx1) * 32 + gq * 8];
        } else {
            const u16* vb = vbase + gq * 8;
            v00 = *(const u16x8*)&vb[(size_t)(cy0 * 64 + cx0) * 256];
            v01 = *(const u16x8*)&vb[(size_t)(cy0 * 64 + cx1) * 256];
            v10 = *(const u16x8*)&vb[(size_t)(cy1 * 64 + cx0) * 256];
            v11 = *(const u16x8*)&vb[(size_t)(cy1 * 64 + cx1) * 256];
        }
        #pragma unroll
        for (int j = 0; j < 8; ++j)
            acc[j] += c00 * bf2f(v00[j]) + c01 * bf2f(v01[j])
                    + c10 * bf2f(v10[j]) + c11 * bf2f(v11[j]);
    }
    u16x8 o;
    #pragma unroll
    for (int j = 0; j < 8; ++j) o[j] = f2bf(acc[j]);
    *(u16x8*)&out1[prow * 256 + m * 32 + gq * 8] = o;
}

// ---------------------------------------------------------------------------
extern "C" void kernel_launch(void* const* d_in, const int* in_sizes, int n_in,
                              void* d_out, int out_size, void* d_ws, size_t ws_size,
                              hipStream_t stream) {
    const float* f_recalib = (const float*)d_in[0];
    const float* f_orig    = (const float*)d_in[1];
    const float* offset_w  = (const float*)d_in[2];
    const float* offset_b  = (const float*)d_in[3];
    const float* attn_w    = (const float*)d_in[4];
    const float* attn_b    = (const float*)d_in[5];
    const float* value_w   = (const float*)d_in[6];
    const float* value_b   = (const float*)d_in[7];
    const float* proj_w    = (const float*)d_in[8];
    const float* proj_b    = (const float*)d_in[9];
    const float* mlp_w1    = (const float*)d_in[10];
    const float* mlp_b1    = (const float*)d_in[11];
    const float* mlp_w2    = (const float*)d_in[12];
    const float* mlp_b2    = (const float*)d_in[13];
    float* out = (float*)d_out;

    u16* wsb       = (u16*)d_ws;
    u16* x_pad     = wsb;                  // 8,921,088 u16 (17.8 MB)
    u16* convout   = wsb + 8921088;        // 3,145,728 (6 MB)
    u16* value_bf  = wsb + 12066816;       // 8,388,608 (16 MB)
    u16* out1_bf   = wsb + 20455424;       // 8,388,608 (16 MB)
    u16* wbf       = wsb + 28844032;       // 614,400 (1.2 MB) -> 59 MB total
    u16* out2_bf   = x_pad;                // alias: x_pad dead after conv+value
    u16* h_bf      = wsb + 8921088;        // alias convout+value+out1 (dead), 32 MB

    u16* wconv = wbf;
    u16* wval  = wbf + 221184;
    u16* wproj = wbf + 286720;
    u16* wmlp1 = wbf + 352256;
    u16* wmlp2 = wbf + 483328;

    // 1. fused NCHW->NHWC-pad conversion + weight prep
    to_nhwc_pad<<<dim3(139, 4, 8), 256, 0, stream>>>(
        f_recalib, x_pad, offset_w, attn_w, value_w, proj_w, mlp_w1, mlp_w2, wbf);
    // 2. conv3x3 (offsets + attn logits)
    conv3x3_mfma<<<dim3(64, 8), 256, 0, stream>>>(
        x_pad, wconv, offset_b, attn_b, convout);
    // 3. value = 1x1 conv (reads padded image)
    gemm_dbuf<<<dim3(32, 2, 8), 256, 0, stream>>>(x_pad, wval, value_b, nullptr,
                                                  nullptr, value_bf, 256, 256, 0, 1);
    // 4. softmax + grid sample + weighted sum
    sample_attend_bf<<<dim3(64, 8, 8), 256, 0, stream>>>(value_bf, convout, out1_bf);
    // 5. proj + f_orig -> out2_bf (bf16 NHWC only)
    gemm_dbuf<<<dim3(32, 2, 8), 256, 0, stream>>>(out1_bf, wproj, proj_b, f_orig,
                                                  nullptr, out2_bf, 256, 256, 4, 0);
    // 6. h = relu(mlp1(out2))
    gemm_dbuf<<<dim3(32, 4, 8), 256, 0, stream>>>(out2_bf, wmlp1, mlp_b1, nullptr,
                                                  nullptr, h_bf, 256, 512, 1, 0);
    // 7. out = mlp2(h) + out2 (NHWC resid) -> f32 NCHW
    gemm_dbuf<<<dim3(32, 2, 8), 256, 0, stream>>>(h_bf, wmlp2, mlp_b2, out2_bf,
                                                  out, nullptr, 512, 256, 6, 0);
}